// Round 3
// baseline (45.804 us; speedup 1.0000x reference)
//
#include <hip/hip_runtime.h>
#include <stdint.h>
#include <float.h>

typedef unsigned long long u64;

#define KK 64
#define NN 128
#define NPAIR 2016
#define NCAND 2081   // 1 + 64 + 2016

// One wave (64 lanes) per batch item. Row r of the generator matrix lives in
// lane r's registers as a 128-bit bitset (2 x u64). All __syncthreads are in a
// single-wave workgroup (elided / near-free); cross-lane LDS is wave-in-order.
__global__ __launch_bounds__(64) void osd_kernel(
    const float* __restrict__ llr_g,
    const float* __restrict__ gm_g,
    float* __restrict__ out_g)
{
    const int b    = blockIdx.x;
    const int lane = threadIdx.x;    // 0..63

    __shared__ float llr_ch[NN];     // clipped llr, original column order
    __shared__ float aabs[NN];       // |llr_ch|
    __shared__ int   idx_sort[NN];   // reliability permutation (desc |llr|, stable)
    __shared__ int   piv[KK];
    __shared__ int   keyArr[NN];
    __shared__ int   mrb[NN];        // MRB column permutation (in sorted-col space)
    __shared__ float w[NN];          // |llr| in final order
    __shared__ u64   Rl[KK][2];      // gm_mrb rows as bitsets
    __shared__ float lut[16][256];   // per-byte subset sums of w
    __shared__ unsigned short pairTab[NPAIR];

    // ---- 1. load + clip llr (2 elements per lane) ----
    float lv0 = llr_g[b * NN + lane];
    float lv1 = llr_g[b * NN + 64 + lane];
    lv0 = fminf(fmaxf(lv0, -100.0f), 100.0f);
    lv1 = fminf(fmaxf(lv1, -100.0f), 100.0f);
    llr_ch[lane]      = lv0;
    llr_ch[64 + lane] = lv1;
    float a0 = fabsf(lv0), a1 = fabsf(lv1);
    aabs[lane]      = a0;
    aabs[64 + lane] = a1;

    // ---- 2. gm -> bitsets via ballot; lane keeps row `lane` as (o0,o1) ----
    u64 o0 = 0, o1 = 0;
    #pragma unroll 16
    for (int h = 0; h < 2 * KK; ++h) {
        float v = gm_g[h * 64 + lane];           // coalesced 256B per instr
        u64 m = __ballot(v != 0.0f);             // bit l = row (h>>1), col (h&1)*64+l
        if (h == 2 * lane)     o0 = m;
        if (h == 2 * lane + 1) o1 = m;
    }
    __syncthreads();

    // ---- 3. stable rank sort by descending |llr| (2 ranks per lane) ----
    int r0 = 0, r1 = 0;
    #pragma unroll 16
    for (int j = 0; j < NN; ++j) {
        float aj = aabs[j];                      // broadcast read
        r0 += (aj > a0) || (aj == a0 && j < lane);
        r1 += (aj > a1) || (aj == a1 && j < 64 + lane);
    }
    idx_sort[r0] = lane;
    idx_sort[r1] = 64 + lane;
    __syncthreads();

    // ---- 4. permute own row into reliability order ----
    u64 g0 = 0, g1 = 0;
    #pragma unroll 16
    for (int j = 0; j < 64; ++j) {
        int c = idx_sort[j];
        u64 bit = ((c < 64) ? (o0 >> c) : (o1 >> (c - 64))) & 1ull;
        g0 |= bit << j;
    }
    #pragma unroll 16
    for (int j = 64; j < NN; ++j) {
        int c = idx_sort[j];
        u64 bit = ((c < 64) ? (o0 >> c) : (o1 >> (c - 64))) & 1ull;
        g1 |= bit << (j - 64);
    }

    // ---- 5. GF(2) Gaussian elimination, fully in registers ----
    // pivot = first set bit of row ic (0 if row is zero) == jax argmax on 0/1 row
    int pv = 0;
    #pragma unroll 8
    for (int ic = 0; ic < KK; ++ic) {
        u64 rr0 = __shfl(g0, ic);
        u64 rr1 = __shfl(g1, ic);
        int p = rr0 ? (__ffsll(rr0) - 1) : (rr1 ? (63 + __ffsll(rr1)) : 0);
        u64 bit = ((p < 64) ? (g0 >> p) : (g1 >> (p - 64))) & 1ull;
        if (bit && lane != ic) { g0 ^= rr0; g1 ^= rr1; }
        if (lane == ic) pv = p;
    }
    piv[lane] = pv;
    __syncthreads();

    // ---- 6. parity columns: key = col + 128*count(pivots==col); 64 smallest ----
    int cnt0 = 0, cnt1 = 0;
    #pragma unroll 16
    for (int m = 0; m < KK; ++m) {
        int pm = piv[m];
        cnt0 += (pm == lane);
        cnt1 += (pm == 64 + lane);
    }
    int k0 = lane + NN * cnt0;
    int k1 = 64 + lane + NN * cnt1;
    keyArr[lane]      = k0;
    keyArr[64 + lane] = k1;
    __syncthreads();
    mrb[lane] = pv;
    int q0 = 0, q1 = 0;
    #pragma unroll 16
    for (int j = 0; j < NN; ++j) {
        int kj = keyArr[j];
        q0 += (kj < k0);
        q1 += (kj < k1);
    }
    if (q0 < 64) mrb[64 + q0] = lane;
    if (q1 < 64) mrb[64 + q1] = 64 + lane;
    __syncthreads();

    // ---- 7. final-order llr data + hard decisions ----
    int m0i = mrb[lane], m1i = mrb[64 + lane];
    int oc0 = idx_sort[m0i], oc1 = idx_sort[m1i];    // final pos -> original col
    float f0 = llr_ch[oc0], f1 = llr_ch[oc1];
    w[lane]      = fabsf(f0);
    w[64 + lane] = fabsf(f1);
    u64 hb0 = __ballot(f0 < 0.0f);                   // hard decision, positions 0..63
    u64 hb1 = __ballot(f1 < 0.0f);                   // positions 64..127
    __syncthreads();

    // ---- 8. permute eliminated row into MRB order ----
    u64 R0 = 0, R1 = 0;
    #pragma unroll 16
    for (int j = 0; j < 64; ++j) {
        int c = mrb[j];
        u64 bit = ((c < 64) ? (g0 >> c) : (g1 >> (c - 64))) & 1ull;
        R0 |= bit << j;
    }
    #pragma unroll 16
    for (int j = 64; j < NN; ++j) {
        int c = mrb[j];
        u64 bit = ((c < 64) ? (g0 >> c) : (g1 >> (c - 64))) & 1ull;
        R1 |= bit << (j - 64);
    }
    Rl[lane][0] = R0;
    Rl[lane][1] = R1;

    // ---- 9. base codeword = XOR of rows with u_hd==1 (wave butterfly) ----
    u64 hbit = (hb0 >> lane) & 1ull;
    u64 v0 = hbit ? R0 : 0ull;
    u64 v1 = hbit ? R1 : 0ull;
    #pragma unroll
    for (int off = 32; off; off >>= 1) {
        v0 ^= __shfl_xor(v0, off);
        v1 ^= __shfl_xor(v1, off);
    }
    u64 cw0 = v0, cw1 = v1;            // uniform across lanes
    u64 bm0 = cw0 ^ hb0, bm1 = cw1 ^ hb1;   // base mismatch mask

    // ---- 10. byte-subset-sum LUT (nested partial sums) + pair table ----
    {
        int p = lane >> 2;                         // 4 lanes per byte-position
        const float* wp = &w[p * 8];
        float wv0 = wp[0], wv1 = wp[1], wv2 = wp[2], wv3 = wp[3];
        float wv4 = wp[4], wv5 = wp[5], wv6 = wp[6], wv7 = wp[7];
        int hi = lane & 3;                         // bits 6..7 of the mask
        float shi = ((hi & 1) ? wv6 : 0.0f) + ((hi & 2) ? wv7 : 0.0f);
        #pragma unroll
        for (int aa = 0; aa < 8; ++aa) {           // bits 3..5
            float sa = shi + ((aa & 1) ? wv3 : 0.0f)
                           + ((aa & 2) ? wv4 : 0.0f)
                           + ((aa & 4) ? wv5 : 0.0f);
            int base = (hi << 6) | (aa << 3);
            #pragma unroll
            for (int c2 = 0; c2 < 8; ++c2) {       // bits 0..2
                float s = sa + ((c2 & 1) ? wv0 : 0.0f)
                             + ((c2 & 2) ? wv1 : 0.0f)
                             + ((c2 & 4) ? wv2 : 0.0f);
                lut[p][base | c2] = s;
            }
        }
    }
    {
        int i = lane;
        int off = 63 * i - (i * (i - 1)) / 2;
        for (int j = i + 1; j < 64; ++j)
            pairTab[off + (j - i - 1)] = (unsigned short)((i << 8) | j);
    }
    __syncthreads();

    // ---- 11. candidate search ----
    // argmin d == argmax S, S = sum_{mismatched}|llr|.  Lexicographic
    // (max S, min id), id order {0=base, 1..64=t1, 65..2080=t2} reproduces the
    // reference's per-round first-argmin + strict-improvement semantics.
    float bestS = -FLT_MAX;
    int bestId  = 0x7fffffff;
    for (int id = lane; id < NCAND; id += 64) {
        u64 m0 = bm0, m1 = bm1;
        if (id >= 65) {
            int pr = pairTab[id - 65];
            int i = pr >> 8, j = pr & 255;
            m0 ^= Rl[i][0] ^ Rl[j][0];
            m1 ^= Rl[i][1] ^ Rl[j][1];
        } else if (id >= 1) {
            m0 ^= Rl[id - 1][0];
            m1 ^= Rl[id - 1][1];
        }
        float s = lut[0][(int)(m0 & 255)]
                + lut[1][(int)((m0 >> 8) & 255)]
                + lut[2][(int)((m0 >> 16) & 255)]
                + lut[3][(int)((m0 >> 24) & 255)]
                + lut[4][(int)((m0 >> 32) & 255)]
                + lut[5][(int)((m0 >> 40) & 255)]
                + lut[6][(int)((m0 >> 48) & 255)]
                + lut[7][(int)((m0 >> 56) & 255)]
                + lut[8][(int)(m1 & 255)]
                + lut[9][(int)((m1 >> 8) & 255)]
                + lut[10][(int)((m1 >> 16) & 255)]
                + lut[11][(int)((m1 >> 24) & 255)]
                + lut[12][(int)((m1 >> 32) & 255)]
                + lut[13][(int)((m1 >> 40) & 255)]
                + lut[14][(int)((m1 >> 48) & 255)]
                + lut[15][(int)((m1 >> 56) & 255)];
        // per-lane ids increase, so '>' keeps the earliest id on ties
        if (s > bestS) { bestS = s; bestId = id; }
    }
    #pragma unroll
    for (int off = 32; off; off >>= 1) {
        float os = __shfl_xor(bestS, off);
        int  oid = __shfl_xor(bestId, off);
        if (os > bestS || (os == bestS && oid < bestId)) { bestS = os; bestId = oid; }
    }
    // all lanes now agree on (bestS, bestId); apply error pattern uniformly
    if (bestId >= 65) {
        int pr = pairTab[bestId - 65];
        int i = pr >> 8, j = pr & 255;
        cw0 ^= Rl[i][0] ^ Rl[j][0];
        cw1 ^= Rl[i][1] ^ Rl[j][1];
    } else if (bestId >= 1) {
        cw0 ^= Rl[bestId - 1][0];
        cw1 ^= Rl[bestId - 1][1];
    }

    // ---- 12. scatter winner back to original column order ----
    out_g[b * NN + oc0] = (float)((cw0 >> lane) & 1ull);
    out_g[b * NN + oc1] = (float)((cw1 >> lane) & 1ull);
}

extern "C" void kernel_launch(void* const* d_in, const int* in_sizes, int n_in,
                              void* d_out, int out_size, void* d_ws, size_t ws_size,
                              hipStream_t stream) {
    const float* llr = (const float*)d_in[0];
    const float* gm  = (const float*)d_in[1];
    float* out       = (float*)d_out;
    int bs = in_sizes[0] / NN;   // 128
    osd_kernel<<<bs, 64, 0, stream>>>(llr, gm, out);
}

// Round 5
// 37.155 us; speedup vs baseline: 1.2328x; 1.2328x over previous
//
#include <hip/hip_runtime.h>
#include <stdint.h>
#include <float.h>

typedef unsigned long long u64;
typedef unsigned int u32;

#define KK 64
#define NN 128
#define NPAIR 2016
#define NCAND 2081   // 1 + 64 + 2016

__device__ __forceinline__ u64 rdlane64(u64 v, int l) {
    u32 lo = (u32)__builtin_amdgcn_readlane((int)(u32)v, l);
    u32 hi = (u32)__builtin_amdgcn_readlane((int)(u32)(v >> 32), l);
    return ((u64)hi << 32) | lo;
}

// One wave per batch item. Row r of the generator matrix lives in lane r's
// registers as 2 x u64. All cross-lane broadcasts with uniform index use
// v_readlane (fast SGPR path) instead of ds_bpermute/LDS.
__global__ __launch_bounds__(64) void osd_kernel(
    const float* __restrict__ llr_g,
    const float* __restrict__ gm_g,
    float* __restrict__ out_g)
{
    const int b    = blockIdx.x;
    const int lane = threadIdx.x;    // 0..63

    __shared__ float llr_ch[NN];         // clipped llr, original column order
    __shared__ int   idx_sort[NN];       // reliability permutation
    __shared__ int   mrbp[KK];           // parity half of MRB permutation
    __shared__ float w[NN];              // |llr| in final order
    __shared__ u32   RlA[KK][5];         // gm_mrb rows; stride 5 (coprime 32) kills gather conflicts
    __shared__ float lut[16][257];       // +1 pad: write bank rotates per row -> 4-way not 64-way
    __shared__ unsigned short pairTab[NPAIR];

    // ---- 1. load + clip llr ----
    float lv0 = llr_g[b * NN + lane];
    float lv1 = llr_g[b * NN + 64 + lane];
    lv0 = fminf(fmaxf(lv0, -100.0f), 100.0f);
    lv1 = fminf(fmaxf(lv1, -100.0f), 100.0f);
    llr_ch[lane]      = lv0;
    llr_ch[64 + lane] = lv1;
    float a0 = fabsf(lv0), a1 = fabsf(lv1);

    // ---- 2. gm -> per-lane row bitsets via ballot + select ----
    u64 o0 = 0, o1 = 0;
    #pragma unroll 32
    for (int h = 0; h < 2 * KK; ++h) {
        float v = gm_g[h * 64 + lane];               // coalesced 256B/instr
        u64 m = __ballot(v != 0.0f);                 // bit l = row (h>>1), col (h&1)*64+l
        if (h == 2 * lane)     o0 = m;               // one cndmask pair each
        if (h == 2 * lane + 1) o1 = m;
    }

    // ---- 3. stable descending ranks, register-only ----
    int r0 = 0, r1 = 0;
    #pragma unroll 8
    for (int j = 0; j < 64; ++j) {
        float aj0 = __int_as_float(__builtin_amdgcn_readlane(__float_as_int(a0), j));
        float aj1 = __int_as_float(__builtin_amdgcn_readlane(__float_as_int(a1), j));
        r0 += (aj0 > a0) || (aj0 == a0 && j < lane);   // elem j vs elem lane
        r0 += (aj1 > a0);                               // elem 64+j: idx always larger
        r1 += (aj0 > a1) || (aj0 == a1);                // elem j vs elem 64+lane: idx always smaller
        r1 += (aj1 > a1) || (aj1 == a1 && j < lane);
    }
    idx_sort[r0] = lane;
    idx_sort[r1] = 64 + lane;

    // ---- 4. permute own row to sorted order (register scatter via ranks) ----
    u64 g0 = 0, g1 = 0;
    #pragma unroll 8
    for (int c = 0; c < 64; ++c) {
        int d0 = __builtin_amdgcn_readlane(r0, c);   // dest of col c (uniform)
        int d1 = __builtin_amdgcn_readlane(r1, c);   // dest of col 64+c
        u64 bb0 = (o0 >> c) & 1ull;
        u64 bb1 = (o1 >> c) & 1ull;
        u64 s0 = bb0 << (d0 & 63);
        u64 s1 = bb1 << (d1 & 63);
        g0 |= (d0 < 64) ? s0 : 0ull;
        g1 |= (d0 < 64) ? 0ull : s0;
        g0 |= (d1 < 64) ? s1 : 0ull;
        g1 |= (d1 < 64) ? 0ull : s1;
    }

    // ---- 5. GF(2) elimination; pivot = first set bit (0 if zero row) ----
    int pv = 0;
    #pragma unroll 4
    for (int ic = 0; ic < KK; ++ic) {
        u64 rr0 = rdlane64(g0, ic);
        u64 rr1 = rdlane64(g1, ic);
        int p = rr0 ? (__ffsll(rr0) - 1) : (rr1 ? (63 + __ffsll(rr1)) : 0);
        u64 bit = ((p < 64) ? (g0 >> p) : (g1 >> (p - 64))) & 1ull;
        bool doit = (bit != 0) && (lane != ic);
        g0 ^= doit ? rr0 : 0ull;
        g1 ^= doit ? rr1 : 0ull;
        if (lane == ic) pv = p;
    }

    // ---- 6. parity ranks: key = col + 128*count(pivots==col); 64 smallest ----
    int cnt0 = 0, cnt1 = 0;
    #pragma unroll 8
    for (int m = 0; m < KK; ++m) {
        int pm = __builtin_amdgcn_readlane(pv, m);
        cnt0 += (pm == lane);
        cnt1 += (pm == 64 + lane);
    }
    int k0 = lane + NN * cnt0;
    int k1 = 64 + lane + NN * cnt1;
    int q0 = 0, q1 = 0;
    #pragma unroll 8
    for (int j = 0; j < 64; ++j) {
        int kj0 = __builtin_amdgcn_readlane(k0, j);
        int kj1 = __builtin_amdgcn_readlane(k1, j);
        q0 += (kj0 < k0) + (kj1 < k0);
        q1 += (kj0 < k1) + (kj1 < k1);
    }
    if (q0 < 64) mrbp[q0] = lane;        // keys are distinct -> exact 64 slots
    if (q1 < 64) mrbp[q1] = 64 + lane;
    __syncthreads();                     // publish idx_sort, mrbp, llr_ch

    // ---- 7. final-order llr + hard decisions ----
    int m1i = mrbp[lane];
    int oc0 = idx_sort[pv];              // mrb[lane] == pv (pivot half in-register)
    int oc1 = idx_sort[m1i];
    float f0 = llr_ch[oc0], f1 = llr_ch[oc1];
    w[lane]      = fabsf(f0);
    w[64 + lane] = fabsf(f1);
    u64 hb0 = __ballot(f0 < 0.0f);       // hard decisions, final positions 0..63
    u64 hb1 = __ballot(f1 < 0.0f);       // positions 64..127

    // ---- 8. permute eliminated row to MRB order ----
    u64 R0 = 0, R1 = 0;
    #pragma unroll 8
    for (int ic = 0; ic < 64; ++ic) {    // pivot half via readlane broadcast of pv
        int c = __builtin_amdgcn_readlane(pv, ic);
        u64 bit = ((c < 64) ? (g0 >> c) : (g1 >> (c - 64))) & 1ull;
        R0 |= bit << ic;
    }
    #pragma unroll 8
    for (int j = 0; j < 64; ++j) {       // parity half via LDS broadcast
        int c = mrbp[j];
        u64 bit = ((c < 64) ? (g0 >> c) : (g1 >> (c - 64))) & 1ull;
        R1 |= bit << j;
    }
    RlA[lane][0] = (u32)R0;
    RlA[lane][1] = (u32)(R0 >> 32);
    RlA[lane][2] = (u32)R1;
    RlA[lane][3] = (u32)(R1 >> 32);

    // ---- 9. base codeword = XOR of rows with u_hd==1 (wave butterfly) ----
    u64 hbit = (hb0 >> lane) & 1ull;
    u64 v0 = hbit ? R0 : 0ull;
    u64 v1 = hbit ? R1 : 0ull;
    #pragma unroll
    for (int off = 32; off; off >>= 1) {
        v0 ^= __shfl_xor(v0, off);
        v1 ^= __shfl_xor(v1, off);
    }
    u64 cw0 = v0, cw1 = v1;                      // uniform
    u64 bmA = cw0 ^ hb0, bmB = cw1 ^ hb1;        // base mismatch mask

    // ---- 10. byte-subset-sum LUT (padded rows) + pair table ----
    {
        int p = lane >> 2;                       // 4 lanes per byte-position
        const float* wp = &w[p * 8];
        float wv0 = wp[0], wv1 = wp[1], wv2 = wp[2], wv3 = wp[3];
        float wv4 = wp[4], wv5 = wp[5], wv6 = wp[6], wv7 = wp[7];
        int hi = lane & 3;                       // mask bits 6..7
        float shi = ((hi & 1) ? wv6 : 0.0f) + ((hi & 2) ? wv7 : 0.0f);
        float* lrow = &lut[p][hi << 6];
        #pragma unroll
        for (int aa = 0; aa < 8; ++aa) {         // bits 3..5
            float sa = shi + ((aa & 1) ? wv3 : 0.0f)
                           + ((aa & 2) ? wv4 : 0.0f)
                           + ((aa & 4) ? wv5 : 0.0f);
            #pragma unroll
            for (int c2 = 0; c2 < 8; ++c2)       // bits 0..2
                lrow[(aa << 3) | c2] = sa + ((c2 & 1) ? wv0 : 0.0f)
                                          + ((c2 & 2) ? wv1 : 0.0f)
                                          + ((c2 & 4) ? wv2 : 0.0f);
        }
    }
    {
        int i = lane;
        int off = 63 * i - (i * (i - 1)) / 2;
        for (int j = i + 1; j < 64; ++j)
            pairTab[off + (j - i - 1)] = (unsigned short)((i << 8) | j);
    }
    __syncthreads();                             // publish w-deps, RlA, lut, pairTab

    // ---- 11. candidate search ----
    // argmin d == argmax S, S = sum_{mismatched}|llr|. Lexicographic
    // (max S, min id), id order {0=base, 1..64=t1, 65..2080=t2} reproduces the
    // reference's per-round first-argmin + strict-improvement semantics.
    u32 bm0 = (u32)bmA, bm1 = (u32)(bmA >> 32);
    u32 bm2 = (u32)bmB, bm3 = (u32)(bmB >> 32);
    float bestS = -FLT_MAX;
    int bestId  = 0x7fffffff;
    #pragma unroll 2
    for (int id = lane; id < NCAND; id += 64) {
        u32 x0 = bm0, x1 = bm1, x2 = bm2, x3 = bm3;
        if (id >= 65) {
            int pr = pairTab[id - 65];
            int i = pr >> 8, j = pr & 255;
            x0 ^= RlA[i][0] ^ RlA[j][0];
            x1 ^= RlA[i][1] ^ RlA[j][1];
            x2 ^= RlA[i][2] ^ RlA[j][2];
            x3 ^= RlA[i][3] ^ RlA[j][3];
        } else if (id >= 1) {
            int i = id - 1;
            x0 ^= RlA[i][0]; x1 ^= RlA[i][1]; x2 ^= RlA[i][2]; x3 ^= RlA[i][3];
        }
        float sA = (lut[0][x0 & 255]          + lut[1][(x0 >> 8) & 255])
                 + (lut[2][(x0 >> 16) & 255]  + lut[3][x0 >> 24]);
        float sB = (lut[4][x1 & 255]          + lut[5][(x1 >> 8) & 255])
                 + (lut[6][(x1 >> 16) & 255]  + lut[7][x1 >> 24]);
        float sC = (lut[8][x2 & 255]          + lut[9][(x2 >> 8) & 255])
                 + (lut[10][(x2 >> 16) & 255] + lut[11][x2 >> 24]);
        float sD = (lut[12][x3 & 255]         + lut[13][(x3 >> 8) & 255])
                 + (lut[14][(x3 >> 16) & 255] + lut[15][x3 >> 24]);
        float s = (sA + sB) + (sC + sD);
        if (s > bestS) { bestS = s; bestId = id; }   // ids ascend: keeps min id on tie
    }
    #pragma unroll
    for (int off = 32; off; off >>= 1) {
        float os = __shfl_xor(bestS, off);
        int  oid = __shfl_xor(bestId, off);
        if (os > bestS || (os == bestS && oid < bestId)) { bestS = os; bestId = oid; }
    }
    // bestId now uniform; apply winning error pattern
    u64 c0 = cw0, c1 = cw1;
    if (bestId >= 65) {
        int pr = pairTab[bestId - 65];
        int i = pr >> 8, j = pr & 255;
        c0 ^= (((u64)RlA[i][1] << 32) | RlA[i][0]) ^ (((u64)RlA[j][1] << 32) | RlA[j][0]);
        c1 ^= (((u64)RlA[i][3] << 32) | RlA[i][2]) ^ (((u64)RlA[j][3] << 32) | RlA[j][2]);
    } else if (bestId >= 1) {
        int i = bestId - 1;
        c0 ^= ((u64)RlA[i][1] << 32) | RlA[i][0];
        c1 ^= ((u64)RlA[i][3] << 32) | RlA[i][2];
    }

    // ---- 12. scatter winner back to original column order ----
    out_g[b * NN + oc0] = (float)((c0 >> lane) & 1ull);
    out_g[b * NN + oc1] = (float)((c1 >> lane) & 1ull);
}

extern "C" void kernel_launch(void* const* d_in, const int* in_sizes, int n_in,
                              void* d_out, int out_size, void* d_ws, size_t ws_size,
                              hipStream_t stream) {
    const float* llr = (const float*)d_in[0];
    const float* gm  = (const float*)d_in[1];
    float* out       = (float*)d_out;
    int bs = in_sizes[0] / NN;   // 128
    osd_kernel<<<bs, 64, 0, stream>>>(llr, gm, out);
}

// Round 6
// 34.317 us; speedup vs baseline: 1.3347x; 1.0827x over previous
//
#include <hip/hip_runtime.h>
#include <stdint.h>
#include <float.h>

typedef unsigned long long u64;
typedef unsigned int u32;

#define KK 64
#define NN 128
#define NPAIR 2016
#define NCAND 2081   // 1 + 64 + 2016

__device__ __forceinline__ u64 rdlane64(u64 v, int l) {
    u32 lo = (u32)__builtin_amdgcn_readlane((int)(u32)v, l);
    u32 hi = (u32)__builtin_amdgcn_readlane((int)(u32)(v >> 32), l);
    return ((u64)hi << 32) | lo;
}

// 4 waves per batch item. Wave 0 runs the serial GF(2) pipeline in registers
// (row r of the matrix in lane r, cross-lane via v_readlane). Waves 1-3
// offload the independent work: gm staging, pairTab, LUT build, and the
// candidate search is split across all 256 threads.
__global__ __launch_bounds__(256) void osd_kernel(
    const float* __restrict__ llr_g,
    const float* __restrict__ gm_g,
    float* __restrict__ out_g)
{
    const int b    = blockIdx.x;
    const int tid  = threadIdx.x;
    const int lane = tid & 63;
    const int wave = tid >> 6;

    __shared__ u64   gorig[2 * KK];      // gm half-rows, original column order
    __shared__ float llr_ch[NN];         // clipped llr, original column order
    __shared__ int   idx_sort[NN];       // reliability permutation
    __shared__ int   mrbp[KK];           // parity half of MRB permutation
    __shared__ float w[NN];              // |llr| in final order
    __shared__ u32   RlA[KK][5];         // gm_mrb rows; stride 5 (coprime 32) kills gather conflicts
    __shared__ float lut[16][257];       // +1 pad: rotates write banks per row
    __shared__ unsigned short pairTab[NPAIR];
    __shared__ u32   sh_bm[4];           // base mismatch mask
    __shared__ u64   sh_cw[2];           // base codeword
    __shared__ u64   wred[4];            // per-wave packed (S,id) reduction

    // wave-0 registers persisted across barriers
    int pv = 0, oc0 = 0, oc1 = 0;
    u64 g0 = 0, g1 = 0;

    // ============ region 0 — parallel across waves ============
    if (wave == 0) {
        // llr load + clip + stable descending ranks (register-only)
        float lv0 = llr_g[b * NN + lane];
        float lv1 = llr_g[b * NN + 64 + lane];
        lv0 = fminf(fmaxf(lv0, -100.0f), 100.0f);
        lv1 = fminf(fmaxf(lv1, -100.0f), 100.0f);
        llr_ch[lane]      = lv0;
        llr_ch[64 + lane] = lv1;
        float a0 = fabsf(lv0), a1 = fabsf(lv1);
        int r0 = 0, r1 = 0;
        #pragma unroll 8
        for (int j = 0; j < 64; ++j) {
            float aj0 = __int_as_float(__builtin_amdgcn_readlane(__float_as_int(a0), j));
            float aj1 = __int_as_float(__builtin_amdgcn_readlane(__float_as_int(a1), j));
            r0 += (aj0 > a0) || (aj0 == a0 && j < lane);   // elem j vs elem lane
            r0 += (aj1 > a0);                               // elem 64+j: idx larger
            r1 += (aj0 > a1) || (aj0 == a1);                // elem j vs 64+lane: idx smaller
            r1 += (aj1 > a1) || (aj1 == a1 && j < lane);
        }
        idx_sort[r0] = lane;
        idx_sort[r1] = 64 + lane;
        g0 = (u64)(u32)r0 | ((u64)(u32)r1 << 32);  // stash ranks (repurposed below)
    } else if (wave == 1) {
        // pair table (static)
        int i = lane;
        int off = 63 * i - (i * (i - 1)) / 2;
        for (int j = i + 1; j < 64; ++j)
            pairTab[off + (j - i - 1)] = (unsigned short)((i << 8) | j);
    } else {
        // waves 2,3: stage gm as bitsets via ballot
        int h0 = (wave - 2) * 64;
        #pragma unroll 16
        for (int hh = 0; hh < 64; ++hh) {
            int h = h0 + hh;
            float v = gm_g[h * 64 + lane];           // coalesced 256B/instr
            u64 m = __ballot(v != 0.0f);             // bit l = row h>>1, col (h&1)*64+l
            if (lane == 0) gorig[h] = m;
        }
    }
    __syncthreads();   // A: gorig, idx_sort, llr_ch, pairTab published

    // ============ region 1 — wave 0 serial pipeline ============
    if (wave == 0) {
        int r0 = (int)(u32)g0, r1 = (int)(u32)(g0 >> 32);
        u64 o0 = gorig[2 * lane], o1 = gorig[2 * lane + 1];

        // permute own row to sorted order (register scatter via ranks)
        g0 = 0; g1 = 0;
        #pragma unroll 8
        for (int c = 0; c < 64; ++c) {
            int d0 = __builtin_amdgcn_readlane(r0, c);   // dest of col c (uniform)
            int d1 = __builtin_amdgcn_readlane(r1, c);   // dest of col 64+c
            u64 bb0 = (o0 >> c) & 1ull;
            u64 bb1 = (o1 >> c) & 1ull;
            u64 s0 = bb0 << (d0 & 63);
            u64 s1 = bb1 << (d1 & 63);
            g0 |= (d0 < 64) ? s0 : 0ull;
            g1 |= (d0 < 64) ? 0ull : s0;
            g0 |= (d1 < 64) ? s1 : 0ull;
            g1 |= (d1 < 64) ? 0ull : s1;
        }

        // GF(2) elimination; pivot = first set bit (0 if zero row)
        #pragma unroll 4
        for (int ic = 0; ic < KK; ++ic) {
            u64 rr0 = rdlane64(g0, ic);
            u64 rr1 = rdlane64(g1, ic);
            int p = rr0 ? (__ffsll(rr0) - 1) : (rr1 ? (63 + __ffsll(rr1)) : 0);
            u64 bit = ((p < 64) ? (g0 >> p) : (g1 >> (p - 64))) & 1ull;
            bool doit = (bit != 0) && (lane != ic);
            g0 ^= doit ? rr0 : 0ull;
            g1 ^= doit ? rr1 : 0ull;
            if (lane == ic) pv = p;
        }

        // parity ranks: key = col + 128*count(pivots==col); 64 smallest
        int cnt0 = 0, cnt1 = 0;
        #pragma unroll 8
        for (int m = 0; m < KK; ++m) {
            int pm = __builtin_amdgcn_readlane(pv, m);
            cnt0 += (pm == lane);
            cnt1 += (pm == 64 + lane);
        }
        int k0 = lane + NN * cnt0;
        int k1 = 64 + lane + NN * cnt1;
        int q0 = 0, q1 = 0;
        #pragma unroll 8
        for (int j = 0; j < 64; ++j) {
            int kj0 = __builtin_amdgcn_readlane(k0, j);
            int kj1 = __builtin_amdgcn_readlane(k1, j);
            q0 += (kj0 < k0) + (kj1 < k0);
            q1 += (kj0 < k1) + (kj1 < k1);
        }
        if (q0 < 64) mrbp[q0] = lane;        // keys distinct -> exact 64 slots
        if (q1 < 64) mrbp[q1] = 64 + lane;
        // same-wave LDS ops are in program order: safe to read mrbp below

        // final-order llr + hard decisions
        int m1i = mrbp[lane];
        oc0 = idx_sort[pv];                  // mrb[lane] == pv
        oc1 = idx_sort[m1i];
        float f0 = llr_ch[oc0], f1 = llr_ch[oc1];
        w[lane]      = fabsf(f0);
        w[64 + lane] = fabsf(f1);
        u64 hb0 = __ballot(f0 < 0.0f);       // hard decisions, final pos 0..63
        u64 hb1 = __ballot(f1 < 0.0f);       // pos 64..127

        // permute eliminated row to MRB order
        u64 R0 = 0, R1 = 0;
        #pragma unroll 8
        for (int ic = 0; ic < 64; ++ic) {    // pivot half via readlane of pv
            int c = __builtin_amdgcn_readlane(pv, ic);
            u64 bit = ((c < 64) ? (g0 >> c) : (g1 >> (c - 64))) & 1ull;
            R0 |= bit << ic;
        }
        #pragma unroll 8
        for (int j = 0; j < 64; ++j) {       // parity half via LDS broadcast
            int c = mrbp[j];
            u64 bit = ((c < 64) ? (g0 >> c) : (g1 >> (c - 64))) & 1ull;
            R1 |= bit << j;
        }
        RlA[lane][0] = (u32)R0;
        RlA[lane][1] = (u32)(R0 >> 32);
        RlA[lane][2] = (u32)R1;
        RlA[lane][3] = (u32)(R1 >> 32);

        // base codeword = XOR of rows with u_hd==1 (wave butterfly)
        u64 hbit = (hb0 >> lane) & 1ull;
        u64 v0 = hbit ? R0 : 0ull;
        u64 v1 = hbit ? R1 : 0ull;
        #pragma unroll
        for (int off = 32; off; off >>= 1) {
            v0 ^= __shfl_xor(v0, off);
            v1 ^= __shfl_xor(v1, off);
        }
        if (lane == 0) {
            sh_cw[0] = v0; sh_cw[1] = v1;
            u64 bmA = v0 ^ hb0, bmB = v1 ^ hb1;
            sh_bm[0] = (u32)bmA; sh_bm[1] = (u32)(bmA >> 32);
            sh_bm[2] = (u32)bmB; sh_bm[3] = (u32)(bmB >> 32);
        }
    }
    __syncthreads();   // B: w, RlA, sh_bm, sh_cw published

    // ============ region 2 — LUT build, all 256 threads ============
    {
        int p = tid >> 4;                        // table row 0..15
        int t = tid & 15;                        // mask bits 4..7
        const float* wp = &w[p * 8];
        float wv0 = wp[0], wv1 = wp[1], wv2 = wp[2], wv3 = wp[3];
        float wv4 = wp[4], wv5 = wp[5], wv6 = wp[6], wv7 = wp[7];
        float st = ((t & 1) ? wv4 : 0.0f) + ((t & 2) ? wv5 : 0.0f)
                 + ((t & 4) ? wv6 : 0.0f) + ((t & 8) ? wv7 : 0.0f);
        float* lrow = &lut[p][t << 4];
        #pragma unroll
        for (int lo = 0; lo < 16; ++lo)
            lrow[lo] = st + ((lo & 1) ? wv0 : 0.0f) + ((lo & 2) ? wv1 : 0.0f)
                          + ((lo & 4) ? wv2 : 0.0f) + ((lo & 8) ? wv3 : 0.0f);
    }
    __syncthreads();   // C: lut published

    // ============ region 3 — candidate search, all 256 threads ============
    // argmin d == argmax S, S = sum_{mismatched}|llr|. Lexicographic
    // (max S, min id), id order {0=base, 1..64=t1, 65..2080=t2} reproduces the
    // reference's per-round first-argmin + strict-improvement semantics.
    u32 bm0 = sh_bm[0], bm1 = sh_bm[1], bm2 = sh_bm[2], bm3 = sh_bm[3];
    float bestS = -1.0f;                 // every thread sees >=8 real candidates (S>=0)
    int bestId  = 0x7fffffff;
    #pragma unroll 2
    for (int id = tid; id < NCAND; id += 256) {
        u32 x0 = bm0, x1 = bm1, x2 = bm2, x3 = bm3;
        if (id >= 65) {
            int pr = pairTab[id - 65];
            int i = pr >> 8, j = pr & 255;
            x0 ^= RlA[i][0] ^ RlA[j][0];
            x1 ^= RlA[i][1] ^ RlA[j][1];
            x2 ^= RlA[i][2] ^ RlA[j][2];
            x3 ^= RlA[i][3] ^ RlA[j][3];
        } else if (id >= 1) {
            int i = id - 1;
            x0 ^= RlA[i][0]; x1 ^= RlA[i][1]; x2 ^= RlA[i][2]; x3 ^= RlA[i][3];
        }
        float sA = (lut[0][x0 & 255]          + lut[1][(x0 >> 8) & 255])
                 + (lut[2][(x0 >> 16) & 255]  + lut[3][x0 >> 24]);
        float sB = (lut[4][x1 & 255]          + lut[5][(x1 >> 8) & 255])
                 + (lut[6][(x1 >> 16) & 255]  + lut[7][x1 >> 24]);
        float sC = (lut[8][x2 & 255]          + lut[9][(x2 >> 8) & 255])
                 + (lut[10][(x2 >> 16) & 255] + lut[11][x2 >> 24]);
        float sD = (lut[12][x3 & 255]         + lut[13][(x3 >> 8) & 255])
                 + (lut[14][(x3 >> 16) & 255] + lut[15][x3 >> 24]);
        float s = (sA + sB) + (sC + sD);
        if (s > bestS) { bestS = s; bestId = id; }   // ids ascend: min id on tie
    }
    // pack (S, id): S>=0 so float bits are unsigned-monotone; low word favors min id
    u64 key = ((u64)(u32)__float_as_int(bestS) << 32)
            | (u32)(0x7fffffff - bestId);
    #pragma unroll
    for (int off = 32; off; off >>= 1) {
        u64 ok = __shfl_xor(key, off);
        key = (ok > key) ? ok : key;
    }
    if (lane == 0) wred[wave] = key;
    __syncthreads();   // D: per-wave winners published

    // ============ region 4 — final pick + output, wave 0 ============
    if (wave == 0) {
        u64 ka = wred[0], kb = wred[1], kc = wred[2], kd = wred[3];
        u64 km = ka > kb ? ka : kb;
        u64 kn = kc > kd ? kc : kd;
        u64 kk = km > kn ? km : kn;
        int bId = 0x7fffffff - (int)(u32)(kk & 0xffffffffull);
        u64 c0 = sh_cw[0], c1 = sh_cw[1];
        if (bId >= 65) {
            int pr = pairTab[bId - 65];
            int i = pr >> 8, j = pr & 255;
            c0 ^= (((u64)RlA[i][1] << 32) | RlA[i][0]) ^ (((u64)RlA[j][1] << 32) | RlA[j][0]);
            c1 ^= (((u64)RlA[i][3] << 32) | RlA[i][2]) ^ (((u64)RlA[j][3] << 32) | RlA[j][2]);
        } else if (bId >= 1) {
            int i = bId - 1;
            c0 ^= ((u64)RlA[i][1] << 32) | RlA[i][0];
            c1 ^= ((u64)RlA[i][3] << 32) | RlA[i][2];
        }
        out_g[b * NN + oc0] = (float)((c0 >> lane) & 1ull);
        out_g[b * NN + oc1] = (float)((c1 >> lane) & 1ull);
    }
}

extern "C" void kernel_launch(void* const* d_in, const int* in_sizes, int n_in,
                              void* d_out, int out_size, void* d_ws, size_t ws_size,
                              hipStream_t stream) {
    const float* llr = (const float*)d_in[0];
    const float* gm  = (const float*)d_in[1];
    float* out       = (float*)d_out;
    int bs = in_sizes[0] / NN;   // 128
    osd_kernel<<<bs, 256, 0, stream>>>(llr, gm, out);
}